// Round 2
// baseline (2080.116 us; speedup 1.0000x reference)
//
#include <hip/hip_runtime.h>
#include <hip/hip_bf16.h>
#include <math.h>

// Problem constants (reference: B=2, T=2048, D=1024, H=16, DH=64)
#define B_  2
#define T_  2048
#define D_  1024
#define H_  16
#define DH_ 64

// ---------------------------------------------------------------------------
// GEMM: C[m,n] = sum_k A[m,k] * W[n,k]   (i.e. C = A @ W^T, W row-major [N,K])
// Tile 64x64, BK=32, 256 threads, 4x4 strided micro-tile.
// ---------------------------------------------------------------------------
#define BM 64
#define BN 64
#define BK 32
#define APAD 4

__global__ __launch_bounds__(256)
void gemm_xwT(const float* __restrict__ A, const float* __restrict__ W,
              float* __restrict__ C, int M, int N, int K) {
  __shared__ float As[BM][BK + APAD];
  __shared__ float Ws[BN][BK + APAD];
  const int tid = threadIdx.x;
  const int ty = tid >> 4;   // 0..15
  const int tx = tid & 15;   // 0..15
  const int row0 = blockIdx.y * BM;
  const int col0 = blockIdx.x * BN;
  const int lr = tid >> 2;   // 0..63 (load row)
  const int ls = tid & 3;    // 0..3  (load segment)

  float acc[4][4];
#pragma unroll
  for (int i = 0; i < 4; ++i)
#pragma unroll
    for (int j = 0; j < 4; ++j) acc[i][j] = 0.f;

  for (int k0 = 0; k0 < K; k0 += BK) {
    const float4* Ag = (const float4*)(A + (size_t)(row0 + lr) * K + k0);
    const float4* Wg = (const float4*)(W + (size_t)(col0 + lr) * K + k0);
    float4 av0 = Ag[ls], av1 = Ag[ls + 4];
    float4 wv0 = Wg[ls], wv1 = Wg[ls + 4];
    *(float4*)&As[lr][ls * 4]      = av0;
    *(float4*)&As[lr][16 + ls * 4] = av1;
    *(float4*)&Ws[lr][ls * 4]      = wv0;
    *(float4*)&Ws[lr][16 + ls * 4] = wv1;
    __syncthreads();

#pragma unroll
    for (int kk = 0; kk < BK; kk += 4) {
      float4 a4[4], b4[4];
#pragma unroll
      for (int i = 0; i < 4; ++i) a4[i] = *(const float4*)&As[ty + 16 * i][kk];
#pragma unroll
      for (int j = 0; j < 4; ++j) b4[j] = *(const float4*)&Ws[tx + 16 * j][kk];
#pragma unroll
      for (int i = 0; i < 4; ++i)
#pragma unroll
        for (int j = 0; j < 4; ++j) {
          acc[i][j] += a4[i].x * b4[j].x + a4[i].y * b4[j].y
                     + a4[i].z * b4[j].z + a4[i].w * b4[j].w;
        }
    }
    __syncthreads();
  }

#pragma unroll
  for (int i = 0; i < 4; ++i) {
    float* Crow = C + (size_t)(row0 + ty + 16 * i) * N + col0;
#pragma unroll
    for (int j = 0; j < 4; ++j) Crow[tx + 16 * j] = acc[i][j];
  }
}

// ---------------------------------------------------------------------------
// RoPE (in-place) on Q and K in [B, T, H, DH] layout.
// q'[i]    = q[i]*cos(t*f_i) - q[i+32]*sin(t*f_i)
// q'[i+32] = q[i+32]*cos(t*f_i) + q[i]*sin(t*f_i),  f_i = 10000^(-i/32)
// ---------------------------------------------------------------------------
__global__ __launch_bounds__(256)
void rope_kernel(float* __restrict__ Q, float* __restrict__ K) {
  const int idx = blockIdx.x * 256 + threadIdx.x;  // exactly B*T*H*32 threads
  const int i = idx & 31;
  const int rest = idx >> 5;             // (b*T + t)*H + h
  const int t = (rest >> 4) & (T_ - 1);  // rest / H  mod T
  const float inv_freq = powf(10000.0f, -(float)i * (1.0f / 32.0f));
  const float ang = (float)t * inv_freq;
  const float c = cosf(ang), s = sinf(ang);
  const size_t base = (size_t)rest * DH_;
  float q1 = Q[base + i], q2 = Q[base + i + 32];
  Q[base + i]      = q1 * c - q2 * s;
  Q[base + i + 32] = q2 * c + q1 * s;
  float k1 = K[base + i], k2 = K[base + i + 32];
  K[base + i]      = k1 * c - k2 * s;
  K[base + i + 32] = k2 * c + k1 * s;
}

// ---------------------------------------------------------------------------
// Flash-style causal attention, fp32.
// Grid: (T/64 q-tiles, B*H). Block: 256 threads = 4 threads per query row.
// Q row in registers (scaled by 1/8); K/V tiles + P in LDS.
// Key mapping: thread tk owns keys kk = j*4 + tk  (bank-conflict-free K reads).
// ---------------------------------------------------------------------------
#define QB 64
#define KB 64

__global__ __launch_bounds__(256)
void attn_kernel(const float* __restrict__ Q, const float* __restrict__ K,
                 const float* __restrict__ V, float* __restrict__ O) {
  __shared__ float Ks[KB][DH_ + 4];
  __shared__ float Vs[KB][DH_ + 4];
  __shared__ float Ps[QB][KB + 1];

  const int qt = blockIdx.x;       // 0..31
  const int bh = blockIdx.y;       // 0..31
  const int b = bh >> 4, h = bh & 15;
  const int tid = threadIdx.x;
  const int tq = tid >> 2;         // 0..63 query row in tile
  const int tk = tid & 3;          // 0..3

  const size_t headoff = (size_t)b * T_ * D_ + (size_t)h * DH_;
  const float* Qb = Q + headoff;
  const float* Kb = K + headoff;
  const float* Vb = V + headoff;
  float*       Ob = O + headoff;

  const int q_glob = qt * QB + tq;

  // Q row -> registers, pre-scaled by 1/sqrt(DH) = 0.125
  float4 qv[16];
  {
    const float4* qrow = (const float4*)(Qb + (size_t)q_glob * D_);
#pragma unroll
    for (int c = 0; c < 16; ++c) {
      float4 x = qrow[c];
      x.x *= 0.125f; x.y *= 0.125f; x.z *= 0.125f; x.w *= 0.125f;
      qv[c] = x;
    }
  }

  float m = -3.0e38f, l = 0.f;
  float acc[16];
#pragma unroll
  for (int d = 0; d < 16; ++d) acc[d] = 0.f;

  for (int kt = 0; kt <= qt; ++kt) {
    // stage K,V tiles (64 rows x 64 floats each)
    for (int e = tid; e < KB * 16; e += 256) {
      const int r = e >> 4, c = e & 15;
      const size_t g = (size_t)(kt * KB + r) * D_ + c * 4;
      *(float4*)&Ks[r][c * 4] = *(const float4*)&Kb[g];
      *(float4*)&Vs[r][c * 4] = *(const float4*)&Vb[g];
    }
    __syncthreads();

    // scores for this thread's 16 keys: kk = j*4 + tk
    float s[16];
#pragma unroll
    for (int j = 0; j < 16; ++j) s[j] = 0.f;
#pragma unroll
    for (int dc = 0; dc < 16; ++dc) {
      const float4 q4 = qv[dc];
#pragma unroll
      for (int j = 0; j < 16; ++j) {
        const float4 k4 = *(const float4*)&Ks[j * 4 + tk][dc * 4];
        s[j] += q4.x * k4.x + q4.y * k4.y + q4.z * k4.z + q4.w * k4.w;
      }
    }

    // causal mask (diagonal tile only) + local max
    float mloc = -3.0e38f;
    if (kt == qt) {
#pragma unroll
      for (int j = 0; j < 16; ++j) {
        const int kg = kt * KB + j * 4 + tk;
        if (kg > q_glob) s[j] = -3.0e38f;
        mloc = fmaxf(mloc, s[j]);
      }
    } else {
#pragma unroll
      for (int j = 0; j < 16; ++j) mloc = fmaxf(mloc, s[j]);
    }
    // reduce max over the 4 lanes of this query row
    mloc = fmaxf(mloc, __shfl_xor(mloc, 1, 4));
    mloc = fmaxf(mloc, __shfl_xor(mloc, 2, 4));
    const float mnew = fmaxf(m, mloc);
    const float alpha = expf(m - mnew);  // 0 on first tile (m = -3e38)

    float ssum = 0.f;
#pragma unroll
    for (int j = 0; j < 16; ++j) {
      const float p = expf(s[j] - mnew);  // masked -> exp(-huge) = 0
      s[j] = p;
      ssum += p;
    }
    ssum += __shfl_xor(ssum, 1, 4);
    ssum += __shfl_xor(ssum, 2, 4);
    l = l * alpha + ssum;
    m = mnew;

#pragma unroll
    for (int j = 0; j < 16; ++j) Ps[tq][j * 4 + tk] = s[j];
#pragma unroll
    for (int d = 0; d < 16; ++d) acc[d] *= alpha;
    __syncthreads();

    // PV: this thread owns output dims [tk*16, tk*16+16)
#pragma unroll 8
    for (int k2 = 0; k2 < KB; ++k2) {
      const float p = Ps[tq][k2];
      const float* vr = &Vs[k2][tk * 16];
      const float4 v0 = *(const float4*)&vr[0];
      const float4 v1 = *(const float4*)&vr[4];
      const float4 v2 = *(const float4*)&vr[8];
      const float4 v3 = *(const float4*)&vr[12];
      acc[0]  += p * v0.x; acc[1]  += p * v0.y; acc[2]  += p * v0.z; acc[3]  += p * v0.w;
      acc[4]  += p * v1.x; acc[5]  += p * v1.y; acc[6]  += p * v1.z; acc[7]  += p * v1.w;
      acc[8]  += p * v2.x; acc[9]  += p * v2.y; acc[10] += p * v2.z; acc[11] += p * v2.w;
      acc[12] += p * v3.x; acc[13] += p * v3.y; acc[14] += p * v3.z; acc[15] += p * v3.w;
    }
    __syncthreads();
  }

  const float invl = 1.0f / l;
  float* orow = Ob + (size_t)q_glob * D_ + tk * 16;
#pragma unroll
  for (int d = 0; d < 16; d += 4) {
    float4 o;
    o.x = acc[d] * invl; o.y = acc[d + 1] * invl;
    o.z = acc[d + 2] * invl; o.w = acc[d + 3] * invl;
    *(float4*)&orow[d] = o;
  }
}

// ---------------------------------------------------------------------------
// kernel_launch: x@Wq^T, x@Wk^T, x@Wv^T -> RoPE(q,k) -> attention -> ao@Wo^T
// ws layout: q | k | v | attn_out, each B*T*D floats (16 MB) = 64 MB total.
// ---------------------------------------------------------------------------
extern "C" void kernel_launch(void* const* d_in, const int* in_sizes, int n_in,
                              void* d_out, int out_size, void* d_ws, size_t ws_size,
                              hipStream_t stream) {
  const float* x  = (const float*)d_in[0];
  const float* Wq = (const float*)d_in[1];
  const float* Wk = (const float*)d_in[2];
  const float* Wv = (const float*)d_in[3];
  const float* Wo = (const float*)d_in[4];
  // d_in[5] = mask: known-causal, not needed.
  float* out = (float*)d_out;

  const size_t NTOK = (size_t)B_ * T_;  // 4096
  float* q  = (float*)d_ws;
  float* k  = q + NTOK * D_;
  float* v  = k + NTOK * D_;
  float* ao = v + NTOK * D_;

  const dim3 gg(D_ / BN, (B_ * T_) / BM);  // (16, 64)
  gemm_xwT<<<gg, 256, 0, stream>>>(x, Wq, q, B_ * T_, D_, D_);
  gemm_xwT<<<gg, 256, 0, stream>>>(x, Wk, k, B_ * T_, D_, D_);
  gemm_xwT<<<gg, 256, 0, stream>>>(x, Wv, v, B_ * T_, D_, D_);

  rope_kernel<<<(B_ * T_ * H_ * 32) / 256, 256, 0, stream>>>(q, k);

  const dim3 ga(T_ / QB, B_ * H_);  // (32, 32)
  attn_kernel<<<ga, 256, 0, stream>>>(q, k, v, ao);

  gemm_xwT<<<gg, 256, 0, stream>>>(ao, Wo, out, B_ * T_, D_, D_);
}

// Round 6
// 360.683 us; speedup vs baseline: 5.7672x; 5.7672x over previous
//
#include <hip/hip_runtime.h>
#include <hip/hip_bf16.h>
#include <math.h>

// Problem constants (reference: B=2, T=2048, D=1024, H=16, DH=64)
#define B_  2
#define T_  2048
#define D_  1024
#define H_  16
#define DH_ 64

typedef __attribute__((ext_vector_type(8))) short bf16x8;
typedef __attribute__((ext_vector_type(4))) float f32x4;

// async global->LDS, 16B per lane; dest = wave-uniform base + lane*16
__device__ __forceinline__ void gll16(const void* g, void* l) {
  __builtin_amdgcn_global_load_lds(
      (const __attribute__((address_space(1))) void*)g,
      (__attribute__((address_space(3))) void*)l, 16, 0, 0);
}

// ---------------------------------------------------------------------------
// f32 -> bf16 elementwise convert (4 elems/thread)
// ---------------------------------------------------------------------------
__global__ __launch_bounds__(256)
void cvt_f32_bf16(const float* __restrict__ in, __hip_bfloat16* __restrict__ out,
                  int n4) {
  const int i = blockIdx.x * 256 + threadIdx.x;
  if (i >= n4) return;
  const float4 a = ((const float4*)in)[i];
  __hip_bfloat16 h0 = __float2bfloat16(a.x);
  __hip_bfloat16 h1 = __float2bfloat16(a.y);
  __hip_bfloat16 h2 = __float2bfloat16(a.z);
  __hip_bfloat16 h3 = __float2bfloat16(a.w);
  ushort4 o;
  o.x = *(unsigned short*)&h0;
  o.y = *(unsigned short*)&h1;
  o.z = *(unsigned short*)&h2;
  o.w = *(unsigned short*)&h3;
  *(ushort4*)(out + (size_t)i * 4) = o;
}

// ---------------------------------------------------------------------------
// bf16 MFMA GEMM: C[m,n] = sum_k A[m,k]*W[n,k], C fp32.  (unchanged from R4)
// 128x128 tile, BK=32, 256 thr = 4 waves, wave quadrant 64x64 (4x4 frags).
// Staging coverage proof: 4 waves x 2 calls x 64 lanes x 16B = 8192 B
//  = 128 rows x 32 bf16 x 2B.  16B-slot swizzle on global source + ds_read.
// ---------------------------------------------------------------------------
__global__ __launch_bounds__(256)
void gemm_bf16_mfma(const __hip_bfloat16* __restrict__ A,
                    const __hip_bfloat16* __restrict__ W,
                    float* __restrict__ C, int M, int N, int K) {
  __shared__ unsigned short As[128 * 32];
  __shared__ unsigned short Bs[128 * 32];
  const int tid = threadIdx.x;
  const int w = tid >> 6;
  const int lane = tid & 63;
  const int lg = lane >> 4;   // 0..3
  const int ln = lane & 15;   // 0..15
  const int wr = w >> 1, wc = w & 1;
  const int row0 = blockIdx.y * 128;
  const int col0 = blockIdx.x * 128;

  const int sr = w * 32 + (lane >> 2);  // + c*16
  const int sp = lane & 3;              // physical 16B slot within 64B row

  f32x4 acc[4][4];
#pragma unroll
  for (int m = 0; m < 4; ++m)
#pragma unroll
    for (int n = 0; n < 4; ++n) acc[m][n] = (f32x4){0.f, 0.f, 0.f, 0.f};

  for (int k0 = 0; k0 < K; k0 += 32) {
#pragma unroll
    for (int c = 0; c < 2; ++c) {
      const int r = sr + c * 16;
      const int ks = sp ^ ((r >> 1) & 3);  // pre-swizzled global slot
      gll16(A + (size_t)(row0 + r) * K + k0 + ks * 8,
            &As[(w * 32 + c * 16) * 32]);
      gll16(W + (size_t)(col0 + r) * K + k0 + ks * 8,
            &Bs[(w * 32 + c * 16) * 32]);
    }
    __syncthreads();  // drains vmcnt before ds_read

    bf16x8 af[4], bfr[4];
#pragma unroll
    for (int m = 0; m < 4; ++m) {
      const int r = wr * 64 + m * 16 + ln;
      af[m] = *(const bf16x8*)&As[r * 32 + (lg ^ ((r >> 1) & 3)) * 8];
    }
#pragma unroll
    for (int n = 0; n < 4; ++n) {
      const int r = wc * 64 + n * 16 + ln;
      bfr[n] = *(const bf16x8*)&Bs[r * 32 + (lg ^ ((r >> 1) & 3)) * 8];
    }
#pragma unroll
    for (int m = 0; m < 4; ++m)
#pragma unroll
      for (int n = 0; n < 4; ++n)
        acc[m][n] = __builtin_amdgcn_mfma_f32_16x16x32_bf16(af[m], bfr[n],
                                                            acc[m][n], 0, 0, 0);
    __syncthreads();  // compute done before next restage
  }

#pragma unroll
  for (int m = 0; m < 4; ++m) {
#pragma unroll
    for (int reg = 0; reg < 4; ++reg) {
      float* crow = C + (size_t)(row0 + wr * 64 + m * 16 + lg * 4 + reg) * N
                    + col0 + wc * 64;
#pragma unroll
      for (int n = 0; n < 4; ++n) crow[n * 16 + ln] = acc[m][n][reg];
    }
  }
}

// ---------------------------------------------------------------------------
// RoPE on fp32 q,k -> bf16 qb,kb.  Q pre-scaled by 1/sqrt(64)=0.125 (exact).
// ---------------------------------------------------------------------------
__global__ __launch_bounds__(256)
void rope_qk_bf16(const float* __restrict__ Q, const float* __restrict__ K,
                  __hip_bfloat16* __restrict__ Qb, __hip_bfloat16* __restrict__ Kb) {
  const int idx = blockIdx.x * 256 + threadIdx.x;  // B*T*H*32 threads
  const int i = idx & 31;
  const int rest = idx >> 5;             // (b*T + t)*H + h
  const int t = (rest >> 4) & (T_ - 1);
  const float inv_freq = powf(10000.0f, -(float)i * (1.0f / 32.0f));
  const float ang = (float)t * inv_freq;
  const float c = cosf(ang), s = sinf(ang);
  const size_t base = (size_t)rest * DH_;
  float q1 = Q[base + i], q2 = Q[base + i + 32];
  Qb[base + i]      = __float2bfloat16((q1 * c - q2 * s) * 0.125f);
  Qb[base + i + 32] = __float2bfloat16((q2 * c + q1 * s) * 0.125f);
  float k1 = K[base + i], k2 = K[base + i + 32];
  Kb[base + i]      = __float2bfloat16(k1 * c - k2 * s);
  Kb[base + i + 32] = __float2bfloat16(k2 * c + k1 * s);
}

// ---------------------------------------------------------------------------
// Flash-style causal attention with bf16 MFMA (fp32 accumulate).
// R5 FIX: Q/K tile staging now 2 iterations (64 rows x 64 bf16 = 8KB needs
// 2 x 256threads x 16B).  R4's single-shot staging left rows 32..63
// uninitialized -> NaN.  Everything else unchanged from the audited source.
// ---------------------------------------------------------------------------
#define SWZ(row, col) ((col) ^ (((row) & 7) << 3))

__global__ __launch_bounds__(256)
void attn_mfma(const __hip_bfloat16* __restrict__ Qb,
               const __hip_bfloat16* __restrict__ Kb,
               const float* __restrict__ V,
               float* __restrict__ O) {
  __shared__ unsigned short Qs[64 * 64];
  __shared__ unsigned short Ks[64 * 64];
  __shared__ unsigned short Vt[64 * 64];     // [d][kk]
  __shared__ unsigned short Ps[4 * 16 * 64]; // per-wave 16x64 P strip

  const int qt = (int)gridDim.x - 1 - (int)blockIdx.x;  // heavy tiles first
  const int bh = blockIdx.y;
  const int b = bh >> 4, h = bh & 15;
  const int tid = threadIdx.x;
  const int w = tid >> 6;
  const int lane = tid & 63;
  const int lg = lane >> 4;   // 0..3
  const int ln = lane & 15;   // 0..15

  const size_t headoff = (size_t)b * T_ * D_ + (size_t)h * DH_;
  const __hip_bfloat16* Qg = Qb + headoff;
  const __hip_bfloat16* Kg = Kb + headoff;
  const float* Vg = V + headoff;
  float* Og = O + headoff;

  // ---- stage Q tile: 64 rows x 64 bf16 (8KB) in 2 passes of 4KB ----
  {
    const int rb = tid >> 3, c0 = (tid & 7) * 8;
#pragma unroll
    for (int it = 0; it < 2; ++it) {
      const int r = it * 32 + rb;
      uint4 x = *(const uint4*)(Qg + (size_t)(qt * 64 + r) * D_ + c0);
      *(uint4*)&Qs[r * 64 + SWZ(r, c0)] = x;
    }
  }
  __syncthreads();

  bf16x8 aQ[2];
#pragma unroll
  for (int ks = 0; ks < 2; ++ks) {
    const int r = w * 16 + ln;
    aQ[ks] = *(const bf16x8*)&Qs[r * 64 + SWZ(r, lg * 8 + 32 * ks)];
  }

  float m_run[4], l_run[4];
  f32x4 accO[4];
#pragma unroll
  for (int r = 0; r < 4; ++r) {
    m_run[r] = -3.0e38f;
    l_run[r] = 0.f;
    accO[r] = (f32x4){0.f, 0.f, 0.f, 0.f};
  }

  for (int kt = 0; kt <= qt; ++kt) {
    __syncthreads();
    // ---- stage K tile: 64 rows x 64 bf16 in 2 passes (R5 fix) ----
    {
      const int rb = tid >> 3, c0 = (tid & 7) * 8;
#pragma unroll
      for (int it = 0; it < 2; ++it) {
        const int r = it * 32 + rb;
        uint4 x = *(const uint4*)(Kg + (size_t)(kt * 64 + r) * D_ + c0);
        *(uint4*)&Ks[r * 64 + SWZ(r, c0)] = x;
      }
    }
    // ---- stage V^T tile from fp32 global (convert + transpose) ----
    {
      const int kk = tid >> 2;
      const int c0 = (tid & 3) * 16;
#pragma unroll
      for (int cc = 0; cc < 16; cc += 4) {
        float4 v4 = *(const float4*)(Vg + (size_t)(kt * 64 + kk) * D_ + c0 + cc);
        const float vv[4] = {v4.x, v4.y, v4.z, v4.w};
#pragma unroll
        for (int j = 0; j < 4; ++j) {
          const int d = c0 + cc + j;
          *(__hip_bfloat16*)&Vt[d * 64 + SWZ(d, kk)] = __float2bfloat16(vv[j]);
        }
      }
    }
    __syncthreads();

    // ---- S = Q K^T (16x64 per wave) ----
    f32x4 sf[4];
#pragma unroll
    for (int cb = 0; cb < 4; ++cb) sf[cb] = (f32x4){0.f, 0.f, 0.f, 0.f};
#pragma unroll
    for (int ks = 0; ks < 2; ++ks) {
#pragma unroll
      for (int cb = 0; cb < 4; ++cb) {
        const int r = cb * 16 + ln;
        bf16x8 bk = *(const bf16x8*)&Ks[r * 64 + SWZ(r, lg * 8 + 32 * ks)];
        sf[cb] = __builtin_amdgcn_mfma_f32_16x16x32_bf16(aQ[ks], bk, sf[cb], 0, 0, 0);
      }
    }

    // ---- causal mask (diagonal tile): col > row -> -inf ----
    if (kt == qt) {
#pragma unroll
      for (int cb = 0; cb < 4; ++cb) {
        const int col = cb * 16 + ln;
#pragma unroll
        for (int reg = 0; reg < 4; ++reg) {
          const int row = w * 16 + lg * 4 + reg;
          if (col > row) sf[cb][reg] = -3.0e38f;
        }
      }
    }

    // ---- online softmax ----
#pragma unroll
    for (int reg = 0; reg < 4; ++reg) {
      float mloc = fmaxf(fmaxf(sf[0][reg], sf[1][reg]),
                         fmaxf(sf[2][reg], sf[3][reg]));
      mloc = fmaxf(mloc, __shfl_xor(mloc, 1, 16));
      mloc = fmaxf(mloc, __shfl_xor(mloc, 2, 16));
      mloc = fmaxf(mloc, __shfl_xor(mloc, 4, 16));
      mloc = fmaxf(mloc, __shfl_xor(mloc, 8, 16));
      const float mnew = fmaxf(m_run[reg], mloc);
      const float alpha = __expf(m_run[reg] - mnew);
      m_run[reg] = mnew;
      float rsum = 0.f;
#pragma unroll
      for (int cb = 0; cb < 4; ++cb) {
        const float p = __expf(sf[cb][reg] - mnew);
        sf[cb][reg] = p;
        rsum += p;
      }
      rsum += __shfl_xor(rsum, 1, 16);
      rsum += __shfl_xor(rsum, 2, 16);
      rsum += __shfl_xor(rsum, 4, 16);
      rsum += __shfl_xor(rsum, 8, 16);
      l_run[reg] = l_run[reg] * alpha + rsum;
#pragma unroll
      for (int db = 0; db < 4; ++db) accO[db][reg] *= alpha;
    }

    // ---- P -> LDS (bf16, per-wave strip) ----
#pragma unroll
    for (int cb = 0; cb < 4; ++cb) {
      const int col = cb * 16 + ln;
#pragma unroll
      for (int reg = 0; reg < 4; ++reg) {
        const int row = lg * 4 + reg;
        *(__hip_bfloat16*)&Ps[w * 1024 + row * 64 + SWZ(row, col)] =
            __float2bfloat16(sf[cb][reg]);
      }
    }

    // ---- O += P V ----
#pragma unroll
    for (int ks = 0; ks < 2; ++ks) {
      bf16x8 ap = *(const bf16x8*)&Ps[w * 1024 + ln * 64 + SWZ(ln, lg * 8 + 32 * ks)];
#pragma unroll
      for (int db = 0; db < 4; ++db) {
        const int r = db * 16 + ln;
        bf16x8 bv = *(const bf16x8*)&Vt[r * 64 + SWZ(r, lg * 8 + 32 * ks)];
        accO[db] = __builtin_amdgcn_mfma_f32_16x16x32_bf16(ap, bv, accO[db], 0, 0, 0);
      }
    }
  }

  // ---- epilogue ----
#pragma unroll
  for (int reg = 0; reg < 4; ++reg) {
    const float inv = 1.0f / l_run[reg];
    const int qrow = qt * 64 + w * 16 + lg * 4 + reg;
#pragma unroll
    for (int db = 0; db < 4; ++db) {
      Og[(size_t)qrow * D_ + db * 16 + ln] = accO[db][reg] * inv;
    }
  }
}

// ---------------------------------------------------------------------------
// kernel_launch. Peak ws = 67.1 MB. Aliasing timeline (stream-ordered):
//   [0,NE) fl:   q fp32        -> ao fp32 (q dead after rope)
//   [NE,2NE):    k fp32        -> aob bf16 (k dead after rope)
//   [2NE,3NE):   v fp32        -> Wob bf16 (v dead after attn)
//   [3NE,4NE):   bf16: xb[0,NE) -> qb; Wq/k/vb -> kb[NE,2NE)
// ---------------------------------------------------------------------------
extern "C" void kernel_launch(void* const* d_in, const int* in_sizes, int n_in,
                              void* d_out, int out_size, void* d_ws, size_t ws_size,
                              hipStream_t stream) {
  const float* x  = (const float*)d_in[0];
  const float* Wq = (const float*)d_in[1];
  const float* Wk = (const float*)d_in[2];
  const float* Wv = (const float*)d_in[3];
  const float* Wo = (const float*)d_in[4];
  float* out = (float*)d_out;

  const size_t NE = (size_t)B_ * T_ * D_;  // 4,194,304
  const size_t WN = (size_t)D_ * D_;       // 1,048,576
  float* q = (float*)d_ws;
  float* k = q + NE;
  float* v = k + NE;
  __hip_bfloat16* bfr = (__hip_bfloat16*)(v + NE);  // 2*NE bf16 capacity
  __hip_bfloat16* xb  = bfr;
  __hip_bfloat16* Wqb = bfr + NE;
  __hip_bfloat16* Wkb = Wqb + WN;
  __hip_bfloat16* Wvb = Wkb + WN;
  __hip_bfloat16* qb  = bfr;       // reuses xb after projection GEMMs
  __hip_bfloat16* kb  = bfr + NE;  // reuses weight slots after GEMMs
  float* ao = q;
  __hip_bfloat16* aob = (__hip_bfloat16*)k;
  __hip_bfloat16* Wob = (__hip_bfloat16*)v;

  const int nbE = (int)(NE / 4 / 256);  // 4096 blocks
  const int nbW = (int)(WN / 4 / 256);  // 1024 blocks

  cvt_f32_bf16<<<nbE, 256, 0, stream>>>(x, xb, (int)(NE / 4));
  cvt_f32_bf16<<<nbW, 256, 0, stream>>>(Wq, Wqb, (int)(WN / 4));
  cvt_f32_bf16<<<nbW, 256, 0, stream>>>(Wk, Wkb, (int)(WN / 4));
  cvt_f32_bf16<<<nbW, 256, 0, stream>>>(Wv, Wvb, (int)(WN / 4));

  const dim3 gg(D_ / 128, (B_ * T_) / 128);  // (8, 32)
  gemm_bf16_mfma<<<gg, 256, 0, stream>>>(xb, Wqb, q, B_ * T_, D_, D_);
  gemm_bf16_mfma<<<gg, 256, 0, stream>>>(xb, Wkb, k, B_ * T_, D_, D_);
  gemm_bf16_mfma<<<gg, 256, 0, stream>>>(xb, Wvb, v, B_ * T_, D_, D_);

  rope_qk_bf16<<<(B_ * T_ * H_ * 32) / 256, 256, 0, stream>>>(q, k, qb, kb);

  const dim3 ga(T_ / 64, B_ * H_);  // (32, 32)
  attn_mfma<<<ga, 256, 0, stream>>>(qb, kb, v, ao);

  cvt_f32_bf16<<<nbE, 256, 0, stream>>>(ao, aob, (int)(NE / 4));
  cvt_f32_bf16<<<nbW, 256, 0, stream>>>(Wo, Wob, (int)(WN / 4));
  gemm_bf16_mfma<<<gg, 256, 0, stream>>>(aob, Wob, out, B_ * T_, D_, D_);
}

// Round 7
// 274.692 us; speedup vs baseline: 7.5725x; 1.3130x over previous
//
#include <hip/hip_runtime.h>
#include <hip/hip_bf16.h>
#include <math.h>

// Problem constants (reference: B=2, T=2048, D=1024, H=16, DH=64)
#define B_  2
#define T_  2048
#define D_  1024
#define H_  16
#define DH_ 64
#define WN_ (D_ * D_)   // 1,048,576 elems per weight

typedef __attribute__((ext_vector_type(8))) short bf16x8;
typedef __attribute__((ext_vector_type(4))) float f32x4;

// async global->LDS, 16B per lane; dest = wave-uniform base + lane*16
__device__ __forceinline__ void gll16(const void* g, void* l) {
  __builtin_amdgcn_global_load_lds(
      (const __attribute__((address_space(1))) void*)g,
      (__attribute__((address_space(3))) void*)l, 16, 0, 0);
}

__device__ __forceinline__ void storeC(float* p, float v) { *p = v; }
__device__ __forceinline__ void storeC(__hip_bfloat16* p, float v) {
  *p = __float2bfloat16(v);
}

// ---------------------------------------------------------------------------
// f32 -> bf16 elementwise convert (4 elems/thread)
// ---------------------------------------------------------------------------
__global__ __launch_bounds__(256)
void cvt_f32_bf16(const float* __restrict__ in, __hip_bfloat16* __restrict__ out,
                  int n4) {
  const int i = blockIdx.x * 256 + threadIdx.x;
  if (i >= n4) return;
  const float4 a = ((const float4*)in)[i];
  __hip_bfloat16 h0 = __float2bfloat16(a.x);
  __hip_bfloat16 h1 = __float2bfloat16(a.y);
  __hip_bfloat16 h2 = __float2bfloat16(a.z);
  __hip_bfloat16 h3 = __float2bfloat16(a.w);
  ushort4 o;
  o.x = *(unsigned short*)&h0;
  o.y = *(unsigned short*)&h1;
  o.z = *(unsigned short*)&h2;
  o.w = *(unsigned short*)&h3;
  *(ushort4*)(out + (size_t)i * 4) = o;
}

// ---------------------------------------------------------------------------
// Wq|Wk|Wv f32 -> one contiguous bf16 [3072][1024]
// ---------------------------------------------------------------------------
__global__ __launch_bounds__(256)
void cvt3_w(const float* __restrict__ Wq, const float* __restrict__ Wk,
            const float* __restrict__ Wv, __hip_bfloat16* __restrict__ out) {
  const int i = blockIdx.x * 256 + threadIdx.x;  // over 3*WN_/4
  const int per = WN_ / 4;                       // 262144 (pow2)
  const int sel = i >> 18;                       // i / per
  const int off = i & (per - 1);
  const float* src = sel == 0 ? Wq : (sel == 1 ? Wk : Wv);
  const float4 a = ((const float4*)src)[off];
  __hip_bfloat16 h0 = __float2bfloat16(a.x);
  __hip_bfloat16 h1 = __float2bfloat16(a.y);
  __hip_bfloat16 h2 = __float2bfloat16(a.z);
  __hip_bfloat16 h3 = __float2bfloat16(a.w);
  ushort4 o;
  o.x = *(unsigned short*)&h0;
  o.y = *(unsigned short*)&h1;
  o.z = *(unsigned short*)&h2;
  o.w = *(unsigned short*)&h3;
  *(ushort4*)(out + (size_t)sel * WN_ + (size_t)off * 4) = o;
}

// ---------------------------------------------------------------------------
// bf16 MFMA GEMM: C[m,n] = sum_k A[m,k]*W[n,k]; C fp32 or bf16.
// 128x128 tile, BK=32, 256 thr = 4 waves, wave quadrant 64x64 (4x4 frags).
// (structure verified in R6; only the C-store is templated now)
// ---------------------------------------------------------------------------
template <typename CT>
__global__ __launch_bounds__(256)
void gemm_bf16_mfma(const __hip_bfloat16* __restrict__ A,
                    const __hip_bfloat16* __restrict__ W,
                    CT* __restrict__ C, int M, int N, int K) {
  __shared__ unsigned short As[128 * 32];
  __shared__ unsigned short Bs[128 * 32];
  const int tid = threadIdx.x;
  const int w = tid >> 6;
  const int lane = tid & 63;
  const int lg = lane >> 4;
  const int ln = lane & 15;
  const int wr = w >> 1, wc = w & 1;
  const int row0 = blockIdx.y * 128;
  const int col0 = blockIdx.x * 128;

  const int sr = w * 32 + (lane >> 2);
  const int sp = lane & 3;

  f32x4 acc[4][4];
#pragma unroll
  for (int m = 0; m < 4; ++m)
#pragma unroll
    for (int n = 0; n < 4; ++n) acc[m][n] = (f32x4){0.f, 0.f, 0.f, 0.f};

  for (int k0 = 0; k0 < K; k0 += 32) {
#pragma unroll
    for (int c = 0; c < 2; ++c) {
      const int r = sr + c * 16;
      const int ks = sp ^ ((r >> 1) & 3);
      gll16(A + (size_t)(row0 + r) * K + k0 + ks * 8,
            &As[(w * 32 + c * 16) * 32]);
      gll16(W + (size_t)(col0 + r) * K + k0 + ks * 8,
            &Bs[(w * 32 + c * 16) * 32]);
    }
    __syncthreads();

    bf16x8 af[4], bfr[4];
#pragma unroll
    for (int m = 0; m < 4; ++m) {
      const int r = wr * 64 + m * 16 + ln;
      af[m] = *(const bf16x8*)&As[r * 32 + (lg ^ ((r >> 1) & 3)) * 8];
    }
#pragma unroll
    for (int n = 0; n < 4; ++n) {
      const int r = wc * 64 + n * 16 + ln;
      bfr[n] = *(const bf16x8*)&Bs[r * 32 + (lg ^ ((r >> 1) & 3)) * 8];
    }
#pragma unroll
    for (int m = 0; m < 4; ++m)
#pragma unroll
      for (int n = 0; n < 4; ++n)
        acc[m][n] = __builtin_amdgcn_mfma_f32_16x16x32_bf16(af[m], bfr[n],
                                                            acc[m][n], 0, 0, 0);
    __syncthreads();
  }

#pragma unroll
  for (int m = 0; m < 4; ++m) {
#pragma unroll
    for (int reg = 0; reg < 4; ++reg) {
      CT* crow = C + (size_t)(row0 + wr * 64 + m * 16 + lg * 4 + reg) * N
                 + col0 + wc * 64;
#pragma unroll
      for (int n = 0; n < 4; ++n) storeC(&crow[n * 16 + ln], acc[m][n][reg]);
    }
  }
}

// ---------------------------------------------------------------------------
// RoPE on bf16 qkv[:, 0:2048] -> qb, kb [B,T,H,64] bf16. Q scaled by 0.125.
// ---------------------------------------------------------------------------
__global__ __launch_bounds__(256)
void rope_qkv(const __hip_bfloat16* __restrict__ qkv,
              __hip_bfloat16* __restrict__ Qb, __hip_bfloat16* __restrict__ Kb) {
  const int idx = blockIdx.x * 256 + threadIdx.x;  // B*T*H*32 threads
  const int i = idx & 31;
  const int rest = idx >> 5;            // (b*T + t)*H + h
  const int row = rest >> 4;            // b*T + t
  const int h = rest & 15;
  const int t = row & (T_ - 1);
  const float inv_freq = powf(10000.0f, -(float)i * (1.0f / 32.0f));
  const float ang = (float)t * inv_freq;
  const float c = cosf(ang), s = sinf(ang);
  const size_t rb = (size_t)row * 3072 + h * 64;
  const float q1 = __bfloat162float(qkv[rb + i]);
  const float q2 = __bfloat162float(qkv[rb + i + 32]);
  const float k1 = __bfloat162float(qkv[rb + 1024 + i]);
  const float k2 = __bfloat162float(qkv[rb + 1024 + i + 32]);
  const size_t base = (size_t)rest * DH_;
  Qb[base + i]      = __float2bfloat16((q1 * c - q2 * s) * 0.125f);
  Qb[base + i + 32] = __float2bfloat16((q2 * c + q1 * s) * 0.125f);
  Kb[base + i]      = __float2bfloat16(k1 * c - k2 * s);
  Kb[base + i + 32] = __float2bfloat16(k2 * c + k1 * s);
}

// ---------------------------------------------------------------------------
// V transpose: qkv[:, 2048:3072] bf16 -> vt [B,H,64,T] bf16 (one-time).
// ---------------------------------------------------------------------------
__global__ __launch_bounds__(256)
void vt_prep(const __hip_bfloat16* __restrict__ qkv,
             __hip_bfloat16* __restrict__ vt) {
  __shared__ unsigned short Ls[64][65];
  const int tt = blockIdx.x;       // t-tile
  const int bh = blockIdx.y;
  const int b = bh >> 4, h = bh & 15;
  const int tid = threadIdx.x;
  const int t0 = tt * 64;
  const int rb = tid >> 3, c0 = (tid & 7) * 8;
#pragma unroll
  for (int it = 0; it < 2; ++it) {
    const int r = it * 32 + rb;  // token row
    uint4 x = *(const uint4*)&qkv[(size_t)(b * T_ + t0 + r) * 3072 + 2048 +
                                  h * 64 + c0];
    const unsigned short* xs = (const unsigned short*)&x;
#pragma unroll
    for (int j = 0; j < 8; ++j) Ls[c0 + j][r] = xs[j];
  }
  __syncthreads();
  const int d = tid >> 2, t8 = (tid & 3) * 16;
  unsigned short tmp[16];
#pragma unroll
  for (int j = 0; j < 16; ++j) tmp[j] = Ls[d][t8 + j];
  __hip_bfloat16* dst = vt + ((size_t)(b * H_ + h) * 64 + d) * T_ + t0 + t8;
  *(uint4*)&dst[0] = *(uint4*)&tmp[0];
  *(uint4*)&dst[8] = *(uint4*)&tmp[8];
}

// ---------------------------------------------------------------------------
// Flash-style causal attention, bf16 MFMA, fp32 accumulate. R7 changes:
//  - V^T pre-transposed in global (vt): staging = vector+swizzle, like K.
//  - reg-staged double-buffer: K/Vt global loads for kt+1 issued right after
//    barrier (b), overlapping compute(kt).
//  - balanced pairing: block bx runs q-tiles {31-bx, bx} -> uniform 33 tiles.
// Compute core (QK^T / mask / softmax / Ps / PV) identical to verified R6.
// ---------------------------------------------------------------------------
#define SWZ(row, col) ((col) ^ (((row) & 7) << 3))

__global__ __launch_bounds__(256)
void attn_mfma(const __hip_bfloat16* __restrict__ Qb,
               const __hip_bfloat16* __restrict__ Kb,
               const __hip_bfloat16* __restrict__ vt,
               __hip_bfloat16* __restrict__ O) {
  __shared__ unsigned short Qs[64 * 64];
  __shared__ unsigned short Ks[64 * 64];
  __shared__ unsigned short Vt[64 * 64];     // [d][kk]
  __shared__ unsigned short Ps[4 * 16 * 64]; // per-wave 16x64 P strip

  const int bx = blockIdx.x;       // 0..15
  const int bh = blockIdx.y;
  const int b = bh >> 4, h = bh & 15;
  const int tid = threadIdx.x;
  const int w = tid >> 6;
  const int lane = tid & 63;
  const int lg = lane >> 4;
  const int ln = lane & 15;

  const size_t headoff = (size_t)b * T_ * D_ + (size_t)h * DH_;
  const __hip_bfloat16* Qg = Qb + headoff;
  const __hip_bfloat16* Kg = Kb + headoff;
  const __hip_bfloat16* vtg = vt + (size_t)(b * H_ + h) * 64 * T_;
  __hip_bfloat16* Og = O + headoff;

  const int rb = tid >> 3, c0 = (tid & 7) * 8;

  for (int pass = 0; pass < 2; ++pass) {
    const int qt = pass ? bx : 31 - bx;  // heavy tile first

    // ---- stage Q tile (Qs unused by any in-flight reader at this point) ----
#pragma unroll
    for (int it = 0; it < 2; ++it) {
      const int r = it * 32 + rb;
      uint4 x = *(const uint4*)(Qg + (size_t)(qt * 64 + r) * D_ + c0);
      *(uint4*)&Qs[r * 64 + SWZ(r, c0)] = x;
    }

    // ---- prologue: tile 0 -> regs ----
    uint4 kreg[2], vreg[2];
#pragma unroll
    for (int it = 0; it < 2; ++it) {
      const int r = it * 32 + rb;
      kreg[it] = *(const uint4*)(Kg + (size_t)r * D_ + c0);
      vreg[it] = *(const uint4*)(vtg + (size_t)r * T_ + c0);
    }

    float m_run[4], l_run[4];
    f32x4 accO[4];
#pragma unroll
    for (int r = 0; r < 4; ++r) {
      m_run[r] = -3.0e38f;
      l_run[r] = 0.f;
      accO[r] = (f32x4){0.f, 0.f, 0.f, 0.f};
    }
    bf16x8 aQ[2];

    for (int kt = 0; kt <= qt; ++kt) {
      __syncthreads();  // (a) prev compute done; Qs writes visible
#pragma unroll
      for (int it = 0; it < 2; ++it) {
        const int r = it * 32 + rb;
        *(uint4*)&Ks[r * 64 + SWZ(r, c0)] = kreg[it];
        *(uint4*)&Vt[r * 64 + SWZ(r, c0)] = vreg[it];
      }
      __syncthreads();  // (b) K/Vt visible

      if (kt == 0) {
#pragma unroll
        for (int ks = 0; ks < 2; ++ks) {
          const int r = w * 16 + ln;
          aQ[ks] = *(const bf16x8*)&Qs[r * 64 + SWZ(r, lg * 8 + 32 * ks)];
        }
      }
      if (kt < qt) {  // overlap next-tile loads with compute below
#pragma unroll
        for (int it = 0; it < 2; ++it) {
          const int r = it * 32 + rb;
          kreg[it] = *(const uint4*)(Kg + (size_t)((kt + 1) * 64 + r) * D_ + c0);
          vreg[it] = *(const uint4*)(vtg + (size_t)r * T_ + (kt + 1) * 64 + c0);
        }
      }

      // ---- S = Q K^T (16x64 per wave) ----
      f32x4 sf[4];
#pragma unroll
      for (int cb = 0; cb < 4; ++cb) sf[cb] = (f32x4){0.f, 0.f, 0.f, 0.f};
#pragma unroll
      for (int ks = 0; ks < 2; ++ks) {
#pragma unroll
        for (int cb = 0; cb < 4; ++cb) {
          const int r = cb * 16 + ln;
          bf16x8 bk = *(const bf16x8*)&Ks[r * 64 + SWZ(r, lg * 8 + 32 * ks)];
          sf[cb] = __builtin_amdgcn_mfma_f32_16x16x32_bf16(aQ[ks], bk, sf[cb], 0, 0, 0);
        }
      }

      // ---- causal mask (diagonal tile) ----
      if (kt == qt) {
#pragma unroll
        for (int cb = 0; cb < 4; ++cb) {
          const int col = cb * 16 + ln;
#pragma unroll
          for (int reg = 0; reg < 4; ++reg) {
            const int row = w * 16 + lg * 4 + reg;
            if (col > row) sf[cb][reg] = -3.0e38f;
          }
        }
      }

      // ---- online softmax ----
#pragma unroll
      for (int reg = 0; reg < 4; ++reg) {
        float mloc = fmaxf(fmaxf(sf[0][reg], sf[1][reg]),
                           fmaxf(sf[2][reg], sf[3][reg]));
        mloc = fmaxf(mloc, __shfl_xor(mloc, 1, 16));
        mloc = fmaxf(mloc, __shfl_xor(mloc, 2, 16));
        mloc = fmaxf(mloc, __shfl_xor(mloc, 4, 16));
        mloc = fmaxf(mloc, __shfl_xor(mloc, 8, 16));
        const float mnew = fmaxf(m_run[reg], mloc);
        const float alpha = __expf(m_run[reg] - mnew);
        m_run[reg] = mnew;
        float rsum = 0.f;
#pragma unroll
        for (int cb = 0; cb < 4; ++cb) {
          const float p = __expf(sf[cb][reg] - mnew);
          sf[cb][reg] = p;
          rsum += p;
        }
        rsum += __shfl_xor(rsum, 1, 16);
        rsum += __shfl_xor(rsum, 2, 16);
        rsum += __shfl_xor(rsum, 4, 16);
        rsum += __shfl_xor(rsum, 8, 16);
        l_run[reg] = l_run[reg] * alpha + rsum;
#pragma unroll
        for (int db = 0; db < 4; ++db) accO[db][reg] *= alpha;
      }

      // ---- P -> LDS (bf16, per-wave strip) ----
#pragma unroll
      for (int cb = 0; cb < 4; ++cb) {
        const int col = cb * 16 + ln;
#pragma unroll
        for (int reg = 0; reg < 4; ++reg) {
          const int row = lg * 4 + reg;
          *(__hip_bfloat16*)&Ps[w * 1024 + row * 64 + SWZ(row, col)] =
              __float2bfloat16(sf[cb][reg]);
        }
      }

      // ---- O += P V ----
#pragma unroll
      for (int ks = 0; ks < 2; ++ks) {
        bf16x8 ap =
            *(const bf16x8*)&Ps[w * 1024 + ln * 64 + SWZ(ln, lg * 8 + 32 * ks)];
#pragma unroll
        for (int db = 0; db < 4; ++db) {
          const int r = db * 16 + ln;
          bf16x8 bv = *(const bf16x8*)&Vt[r * 64 + SWZ(r, lg * 8 + 32 * ks)];
          accO[db] = __builtin_amdgcn_mfma_f32_16x16x32_bf16(ap, bv, accO[db], 0, 0, 0);
        }
      }
    }

    // ---- epilogue: normalize, store bf16 ----
#pragma unroll
    for (int reg = 0; reg < 4; ++reg) {
      const float inv = 1.0f / l_run[reg];
      const int qrow = qt * 64 + w * 16 + lg * 4 + reg;
#pragma unroll
      for (int db = 0; db < 4; ++db) {
        Og[(size_t)qrow * D_ + db * 16 + ln] =
            __float2bfloat16(accO[db][reg] * inv);
      }
    }
  }
}

// ---------------------------------------------------------------------------
// kernel_launch. ws layout (bytes; peak 65.1 MB < proven 67.1):
//   A [0, 25.2M):    qkvb bf16 [4096,3072]  -> aob bf16 (after vt_prep/rope)
//   B [25.2, 33.6M): xb bf16
//   C [33.6, 39.9M): Wqkvb bf16 [3072,1024] -> Wob bf16 (after gemm_qkv)
//   D qb, E kb, F vt: bf16 [B,T,H,64] / [B,H,64,T], 8.4 MB each
// ---------------------------------------------------------------------------
extern "C" void kernel_launch(void* const* d_in, const int* in_sizes, int n_in,
                              void* d_out, int out_size, void* d_ws, size_t ws_size,
                              hipStream_t stream) {
  const float* x  = (const float*)d_in[0];
  const float* Wq = (const float*)d_in[1];
  const float* Wk = (const float*)d_in[2];
  const float* Wv = (const float*)d_in[3];
  const float* Wo = (const float*)d_in[4];
  float* out = (float*)d_out;

  const size_t NE = (size_t)B_ * T_ * D_;   // 4,194,304
  char* base = (char*)d_ws;
  __hip_bfloat16* qkvb  = (__hip_bfloat16*)base;                    // 3*NE el
  __hip_bfloat16* xb    = (__hip_bfloat16*)(base + 3 * NE * 2);     // NE el
  __hip_bfloat16* Wqkvb = (__hip_bfloat16*)(base + 4 * NE * 2);     // 3*WN_ el
  __hip_bfloat16* qb    = (__hip_bfloat16*)(base + 4 * NE * 2 + 3ull * WN_ * 2);
  __hip_bfloat16* kb    = qb + NE;
  __hip_bfloat16* vtb   = kb + NE;
  __hip_bfloat16* aob   = qkvb;   // overlays qkvb (dead after rope+vt_prep)
  __hip_bfloat16* Wob   = Wqkvb;  // overlays Wqkvb (dead after gemm_qkv)

  cvt_f32_bf16<<<(int)(NE / 4 / 256), 256, 0, stream>>>(x, xb, (int)(NE / 4));
  cvt3_w<<<3 * WN_ / 4 / 256, 256, 0, stream>>>(Wq, Wk, Wv, Wqkvb);

  const dim3 gq(3 * D_ / 128, (B_ * T_) / 128);  // (24, 32)
  gemm_bf16_mfma<__hip_bfloat16><<<gq, 256, 0, stream>>>(
      xb, Wqkvb, qkvb, B_ * T_, 3 * D_, D_);

  rope_qkv<<<(B_ * T_ * H_ * 32) / 256, 256, 0, stream>>>(qkvb, qb, kb);
  vt_prep<<<dim3(T_ / 64, B_ * H_), 256, 0, stream>>>(qkvb, vtb);

  const dim3 ga(T_ / 128, B_ * H_);  // (16, 32) paired q-tiles
  attn_mfma<<<ga, 256, 0, stream>>>(qb, kb, vtb, aob);

  cvt_f32_bf16<<<WN_ / 4 / 256, 256, 0, stream>>>(Wo, Wob, WN_ / 4);

  const dim3 go(D_ / 128, (B_ * T_) / 128);  // (8, 32)
  gemm_bf16_mfma<float><<<go, 256, 0, stream>>>(aob, Wob, out, B_ * T_, D_, D_);
}